// Round 1
// baseline (376.019 us; speedup 1.0000x reference)
//
#include <hip/hip_runtime.h>
#include <hip/hip_bf16.h>
#include <math.h>

// Problem constants (B=4, S=2048, D=768, H=3072, E=8, K=2, cap_factor=1.5)
#define TOK    8192          // B*S tokens
#define DMODEL 768
#define HDIM   3072
#define NEXP   8
#define CAP    1536          // int((B*S/E)*1.5)
#define NFLAT  (TOK*2)

typedef __attribute__((ext_vector_type(8))) short bf16x8;
typedef __attribute__((ext_vector_type(4))) float f32x4;

static __device__ __forceinline__ unsigned short f2bf(float f) {
  unsigned int u = __float_as_uint(f);
  u += 0x7FFF + ((u >> 16) & 1);          // round-to-nearest-even
  return (unsigned short)(u >> 16);
}

static __device__ __forceinline__ void gld_lds16(const void* g, void* l) {
  __builtin_amdgcn_global_load_lds((const __attribute__((address_space(1))) void*)g,
                                   (__attribute__((address_space(3))) void*)l,
                                   16, 0, 0);
}

// ---------------- 1. Router: fp64 logits, top-2, renormalized weights ----------------
// one wave per token; 4 waves per block
__global__ __launch_bounds__(256)
void moe_router(const float* __restrict__ x, const float* __restrict__ Wr,
                int* __restrict__ eidx, float* __restrict__ pw)
{
  const int wid = threadIdx.x >> 6, lane = threadIdx.x & 63;
  const int t = blockIdx.x * 4 + wid;
  const float* xr = x + (size_t)t * DMODEL;
  double acc[NEXP];
#pragma unroll
  for (int e = 0; e < NEXP; ++e) acc[e] = 0.0;
  for (int j = 0; j < DMODEL / 64; ++j) {
    const int d = j * 64 + lane;
    const double xv = (double)xr[d];
    const float* wrow = Wr + (size_t)d * NEXP;
#pragma unroll
    for (int e = 0; e < NEXP; ++e) acc[e] += xv * (double)wrow[e];
  }
#pragma unroll
  for (int off = 32; off > 0; off >>= 1) {
#pragma unroll
    for (int e = 0; e < NEXP; ++e) acc[e] += __shfl_xor(acc[e], off, 64);
  }
  if (lane == 0) {
    int e0 = 0;
    for (int e = 1; e < NEXP; ++e) if (acc[e] > acc[e0]) e0 = e;           // ties -> lower idx
    int e1 = (e0 == 0) ? 1 : 0;
    for (int e = 0; e < NEXP; ++e) { if (e == e0) continue; if (acc[e] > acc[e1]) e1 = e; }
    const double p0 = 1.0 / (1.0 + exp(acc[e1] - acc[e0]));               // renormalized top-2
    eidx[t * 2 + 0] = e0; eidx[t * 2 + 1] = e1;
    pw[t * 2 + 0] = (float)p0; pw[t * 2 + 1] = (float)(1.0 - p0);
  }
}

// ---------------- 2. Capacity assignment: per-expert exclusive prefix scan ----------------
// one block per expert; thread handles 64 consecutive flat entries (n = t*2 + slot)
__global__ __launch_bounds__(256)
void moe_assign(const int* __restrict__ eidx, int* __restrict__ slotpos,
                int* __restrict__ elist, int* __restrict__ counts)
{
  const int e = blockIdx.x;
  const int tid = threadIdx.x;
  const int base = tid * 64;
  int cnt = 0;
  for (int j = 0; j < 64; ++j) cnt += (eidx[base + j] == e);
  const int lane = tid & 63, wid = tid >> 6;
  int incl = cnt;
  for (int off = 1; off < 64; off <<= 1) {
    int u = __shfl_up(incl, off, 64);
    if (lane >= off) incl += u;
  }
  __shared__ int wsum[4];
  if (lane == 63) wsum[wid] = incl;
  __syncthreads();
  int wbase = 0;
  for (int w = 0; w < wid; ++w) wbase += wsum[w];
  int run = wbase + incl - cnt;                    // exclusive base for my 64 entries
  for (int j = 0; j < 64; ++j) {
    const int n = base + j;
    if (eidx[n] == e) {
      const int pos = run++;
      slotpos[n] = (pos < CAP) ? pos : -1;
      if (pos < CAP) elist[e * CAP + pos] = n >> 1;
    }
  }
  if (tid == 255) {
    int tot = wbase + incl;
    counts[e] = (tot < CAP) ? tot : CAP;
  }
}

// ---------------- 3. Transpose + fp32->bf16 convert (weights) ----------------
// in: [E][R][C] fp32  ->  out: [E][C][R] bf16.  grid: (C/64, R/64, E), block 256
__global__ __launch_bounds__(256)
void transpose_bf16(const float* __restrict__ in, unsigned short* __restrict__ out,
                    int R, int C)
{
  __shared__ unsigned short tile[64][65];
  const int e = blockIdx.z;
  in  += (size_t)e * R * C;
  out += (size_t)e * C * R;
  const int c0 = blockIdx.x * 64;
  const int r0 = blockIdx.y * 64;
  const int tid = threadIdx.x;
#pragma unroll
  for (int i = 0; i < 16; ++i) {
    const int L = tid + i * 256;
    const int r = L >> 6, c = L & 63;
    tile[r][c] = f2bf(in[(size_t)(r0 + r) * C + c0 + c]);
  }
  __syncthreads();
#pragma unroll
  for (int i = 0; i < 16; ++i) {
    const int L = tid + i * 256;
    const int rr = L & 63, cc = L >> 6;
    out[(size_t)(c0 + cc) * R + r0 + rr] = tile[rr][cc];
  }
}

// ---------------- 4. Gather tokens per expert into contiguous bf16 rows ----------------
// grid (CAP, E), block 64
__global__ __launch_bounds__(64)
void moe_gather(const float* __restrict__ x, const int* __restrict__ elist,
                const int* __restrict__ counts, unsigned short* __restrict__ Xg)
{
  const int p = blockIdx.x, e = blockIdx.y;
  const int lane = threadIdx.x;
  unsigned short* dst = Xg + ((size_t)e * CAP + p) * DMODEL;
  if (p >= counts[e]) {
    ushort4 z; z.x = z.y = z.z = z.w = 0;
#pragma unroll
    for (int j = 0; j < 3; ++j) ((ushort4*)dst)[j * 64 + lane] = z;
    return;
  }
  const int tok = elist[e * CAP + p];
  const float4* src = (const float4*)(x + (size_t)tok * DMODEL);
#pragma unroll
  for (int j = 0; j < 3; ++j) {
    float4 v = src[j * 64 + lane];
    ushort4 o;
    o.x = f2bf(v.x); o.y = f2bf(v.y); o.z = f2bf(v.z); o.w = f2bf(v.w);
    ((ushort4*)dst)[j * 64 + lane] = o;
  }
}

// ---------------- 5. Grouped GEMM: C[m,n] = A[m,:] . B[n,:]  (B stored n-major) ----------------
// EPI=0: C = bf16( gelu_exact(acc + bias[n]) )   (hidden)
// EPI=1: C = f32 ( acc + bias[n] )               (expert output)
// 128x128 tile, BK=64, 256 threads (4 waves, 2x2), mfma_f32_16x16x32_bf16
template <int EPI>
__global__ __launch_bounds__(256)
void moe_gemm(const unsigned short* __restrict__ A, int lda,
              const unsigned short* __restrict__ Bn, int ldb,
              void* __restrict__ Cout, int ldc,
              const float* __restrict__ bias,
              int Ksize, int Nsize)
{
  __shared__ __align__(16) unsigned short Al[128 * 64];
  __shared__ __align__(16) unsigned short Bl[128 * 64];

  const int e = blockIdx.z;
  const int m0 = blockIdx.y * 128;
  const int n0 = blockIdx.x * 128;
  A  += (size_t)e * CAP * lda;
  Bn += (size_t)e * Nsize * ldb;
  const float* bvec = bias + (size_t)e * Nsize;

  const int tid = threadIdx.x;
  const int lane = tid & 63;
  const int wid = tid >> 6;
  const int wr = wid >> 1, wc = wid & 1;    // 2x2 wave grid, each wave 64x64
  const int r16 = lane & 15, g = lane >> 4;

  f32x4 acc[4][4];
#pragma unroll
  for (int i = 0; i < 4; ++i)
#pragma unroll
    for (int j = 0; j < 4; ++j) acc[i][j] = (f32x4){0.f, 0.f, 0.f, 0.f};

  for (int k0 = 0; k0 < Ksize; k0 += 64) {
    // stage 128x64 bf16 tiles (16 KB each) via global_load_lds width=16
#pragma unroll
    for (int r = 0; r < 4; ++r) {
      const int c = r * 256 + tid;            // chunk id: row = c>>3, 16B-col = c&7
      const int row = c >> 3, col = c & 7;
      const unsigned short* ga = A + (size_t)(m0 + row) * lda + k0 + col * 8;
      unsigned short* la = Al + (size_t)(r * 256 + wid * 64) * 8;   // wave-uniform base
      gld_lds16(ga, la);
      const unsigned short* gb = Bn + (size_t)(n0 + row) * ldb + k0 + col * 8;
      unsigned short* lb = Bl + (size_t)(r * 256 + wid * 64) * 8;
      gld_lds16(gb, lb);
    }
    __syncthreads();
#pragma unroll
    for (int kk = 0; kk < 64; kk += 32) {
      bf16x8 af[4], bf[4];
#pragma unroll
      for (int mi = 0; mi < 4; ++mi)
        af[mi] = *(const bf16x8*)&Al[(wr * 64 + mi * 16 + r16) * 64 + kk + 8 * g];
#pragma unroll
      for (int ni = 0; ni < 4; ++ni)
        bf[ni] = *(const bf16x8*)&Bl[(wc * 64 + ni * 16 + r16) * 64 + kk + 8 * g];
#pragma unroll
      for (int mi = 0; mi < 4; ++mi)
#pragma unroll
        for (int ni = 0; ni < 4; ++ni)
          acc[mi][ni] = __builtin_amdgcn_mfma_f32_16x16x32_bf16(af[mi], bf[ni], acc[mi][ni], 0, 0, 0);
    }
    __syncthreads();
  }

  // epilogue: D layout col = lane&15, row = 4*(lane>>4)+reg
#pragma unroll
  for (int ni = 0; ni < 4; ++ni) {
    const int gc = n0 + wc * 64 + ni * 16 + r16;
    const float bv = bvec[gc];
#pragma unroll
    for (int mi = 0; mi < 4; ++mi) {
#pragma unroll
      for (int reg = 0; reg < 4; ++reg) {
        const int gr = m0 + wr * 64 + mi * 16 + 4 * g + reg;
        float v = acc[mi][ni][reg] + bv;
        if (EPI == 0) {
          v = 0.5f * v * (1.0f + erff(v * 0.70710678118654752f));   // exact gelu
          ((unsigned short*)Cout)[(size_t)e * CAP * ldc + (size_t)gr * ldc + gc] = f2bf(v);
        } else {
          ((float*)Cout)[(size_t)e * CAP * ldc + (size_t)gr * ldc + gc] = v;
        }
      }
    }
  }
}

// ---------------- 6. Combine: out[t] = sum over kept slots w * Y[e][pos] ----------------
// one block (192 threads = 768/4) per token
__global__ __launch_bounds__(192)
void moe_combine(const float* __restrict__ Y, const int* __restrict__ eidx,
                 const float* __restrict__ pw, const int* __restrict__ slotpos,
                 float* __restrict__ out)
{
  const int t = blockIdx.x;
  const int tid = threadIdx.x;
  float4 acc; acc.x = acc.y = acc.z = acc.w = 0.f;
#pragma unroll
  for (int s = 0; s < 2; ++s) {
    const int pos = slotpos[t * 2 + s];
    if (pos >= 0) {
      const int e = eidx[t * 2 + s];
      const float w = pw[t * 2 + s];
      float4 y = ((const float4*)(Y + ((size_t)e * CAP + pos) * DMODEL))[tid];
      acc.x += w * y.x; acc.y += w * y.y; acc.z += w * y.z; acc.w += w * y.w;
    }
  }
  ((float4*)out)[(size_t)t * (DMODEL / 4) + tid] = acc;
}

// ---------------- launch ----------------
extern "C" void kernel_launch(void* const* d_in, const int* in_sizes, int n_in,
                              void* d_out, int out_size, void* d_ws, size_t ws_size,
                              hipStream_t stream)
{
  const float* x  = (const float*)d_in[0];
  const float* Wr = (const float*)d_in[1];
  const float* w1 = (const float*)d_in[2];
  const float* b1 = (const float*)d_in[3];
  const float* w2 = (const float*)d_in[4];
  const float* b2 = (const float*)d_in[5];
  float* out = (float*)d_out;

  char* ws = (char*)d_ws;
  const size_t SZ_W1T  = (size_t)NEXP * HDIM * DMODEL * 2;   // 37,748,736
  const size_t SZ_W2T  = (size_t)NEXP * DMODEL * HDIM * 2;   // 37,748,736
  const size_t SZ_XG   = (size_t)NEXP * CAP * DMODEL * 2;    // 18,874,368
  const size_t SZ_H    = (size_t)NEXP * CAP * HDIM * 2;      // 75,497,472
  const size_t SZ_Y    = (size_t)NEXP * CAP * DMODEL * 4;    // 37,748,736
  unsigned short* w1t = (unsigned short*)(ws);                       size_t off = SZ_W1T;
  unsigned short* w2t = (unsigned short*)(ws + off);                 off += SZ_W2T;
  unsigned short* Xg  = (unsigned short*)(ws + off);                 off += SZ_XG;
  unsigned short* Hb  = (unsigned short*)(ws + off);                 off += SZ_H;
  float*          Yb  = (float*)(ws + off);                         off += SZ_Y;
  int*   eidx    = (int*)(ws + off);                                 off += (size_t)TOK * 2 * 4;
  float* pw      = (float*)(ws + off);                               off += (size_t)TOK * 2 * 4;
  int*   slotpos = (int*)(ws + off);                                 off += (size_t)NFLAT * 4;
  int*   elist   = (int*)(ws + off);                                 off += (size_t)NEXP * CAP * 4;
  int*   counts  = (int*)(ws + off);

  // 1. router (fp64 logits -> exact top-2 ordering)
  moe_router<<<TOK / 4, 256, 0, stream>>>(x, Wr, eidx, pw);
  // 2. capacity assignment
  moe_assign<<<NEXP, 256, 0, stream>>>(eidx, slotpos, elist, counts);
  // 3. weight transposes (n-major bf16): w1 [E][D][H] -> w1t [E][H][D]; w2 [E][H][D] -> w2t [E][D][H]
  transpose_bf16<<<dim3(HDIM / 64, DMODEL / 64, NEXP), 256, 0, stream>>>(w1, w1t, DMODEL, HDIM);
  transpose_bf16<<<dim3(DMODEL / 64, HDIM / 64, NEXP), 256, 0, stream>>>(w2, w2t, HDIM, DMODEL);
  // 4. gather per-expert token rows (bf16), zero pad rows
  moe_gather<<<dim3(CAP, NEXP), 64, 0, stream>>>(x, elist, counts, Xg);
  // 5. grouped GEMMs
  moe_gemm<0><<<dim3(HDIM / 128, CAP / 128, NEXP), 256, 0, stream>>>(
      Xg, DMODEL, w1t, DMODEL, Hb, HDIM, b1, DMODEL, HDIM);
  moe_gemm<1><<<dim3(DMODEL / 128, CAP / 128, NEXP), 256, 0, stream>>>(
      Hb, HDIM, w2t, HDIM, Yb, DMODEL, b2, HDIM, DMODEL);
  // 6. weighted combine (deterministic, no atomics)
  moe_combine<<<TOK, 192, 0, stream>>>(Yb, eidx, pw, slotpos, out);
}

// Round 2
// 344.276 us; speedup vs baseline: 1.0922x; 1.0922x over previous
//
#include <hip/hip_runtime.h>
#include <hip/hip_bf16.h>
#include <math.h>

// Problem constants (B=4, S=2048, D=768, H=3072, E=8, K=2, cap_factor=1.5)
#define TOK    8192          // B*S tokens
#define DMODEL 768
#define HDIM   3072
#define NEXP   8
#define CAP    1536          // int((B*S/E)*1.5)
#define NFLAT  (TOK*2)

typedef __attribute__((ext_vector_type(8))) short bf16x8;
typedef __attribute__((ext_vector_type(4))) float f32x4;

static __device__ __forceinline__ unsigned short f2bf(float f) {
  unsigned int u = __float_as_uint(f);
  u += 0x7FFF + ((u >> 16) & 1);          // round-to-nearest-even
  return (unsigned short)(u >> 16);
}

static __device__ __forceinline__ void gld_lds16(const void* g, void* l) {
  __builtin_amdgcn_global_load_lds((const __attribute__((address_space(1))) void*)g,
                                   (__attribute__((address_space(3))) void*)l,
                                   16, 0, 0);
}

#define SBAR() __builtin_amdgcn_s_barrier()
#define LGKM0() do { asm volatile("s_waitcnt lgkmcnt(0)" ::: "memory"); \
                     __builtin_amdgcn_sched_barrier(0); } while (0)
#define VMW0() asm volatile("s_waitcnt vmcnt(0)" ::: "memory")

// ---------------- 1. Router: fp64 logits, top-2, renormalized weights ----------------
__global__ __launch_bounds__(256)
void moe_router(const float* __restrict__ x, const float* __restrict__ Wr,
                int* __restrict__ eidx, float* __restrict__ pw)
{
  const int wid = threadIdx.x >> 6, lane = threadIdx.x & 63;
  const int t = blockIdx.x * 4 + wid;
  const float* xr = x + (size_t)t * DMODEL;
  double acc[NEXP];
#pragma unroll
  for (int e = 0; e < NEXP; ++e) acc[e] = 0.0;
  for (int j = 0; j < DMODEL / 64; ++j) {
    const int d = j * 64 + lane;
    const double xv = (double)xr[d];
    const float* wrow = Wr + (size_t)d * NEXP;
#pragma unroll
    for (int e = 0; e < NEXP; ++e) acc[e] += xv * (double)wrow[e];
  }
#pragma unroll
  for (int off = 32; off > 0; off >>= 1) {
#pragma unroll
    for (int e = 0; e < NEXP; ++e) acc[e] += __shfl_xor(acc[e], off, 64);
  }
  if (lane == 0) {
    int e0 = 0;
    for (int e = 1; e < NEXP; ++e) if (acc[e] > acc[e0]) e0 = e;
    int e1 = (e0 == 0) ? 1 : 0;
    for (int e = 0; e < NEXP; ++e) { if (e == e0) continue; if (acc[e] > acc[e1]) e1 = e; }
    const double p0 = 1.0 / (1.0 + exp(acc[e1] - acc[e0]));
    eidx[t * 2 + 0] = e0; eidx[t * 2 + 1] = e1;
    pw[t * 2 + 0] = (float)p0; pw[t * 2 + 1] = (float)(1.0 - p0);
  }
}

// ---------------- 2. Capacity assignment ----------------
__global__ __launch_bounds__(256)
void moe_assign(const int* __restrict__ eidx, int* __restrict__ slotpos,
                int* __restrict__ elist, int* __restrict__ counts)
{
  const int e = blockIdx.x;
  const int tid = threadIdx.x;
  const int base = tid * 64;
  int cnt = 0;
  for (int j = 0; j < 64; ++j) cnt += (eidx[base + j] == e);
  const int lane = tid & 63, wid = tid >> 6;
  int incl = cnt;
  for (int off = 1; off < 64; off <<= 1) {
    int u = __shfl_up(incl, off, 64);
    if (lane >= off) incl += u;
  }
  __shared__ int wsum[4];
  if (lane == 63) wsum[wid] = incl;
  __syncthreads();
  int wbase = 0;
  for (int w = 0; w < wid; ++w) wbase += wsum[w];
  int run = wbase + incl - cnt;
  for (int j = 0; j < 64; ++j) {
    const int n = base + j;
    if (eidx[n] == e) {
      const int pos = run++;
      slotpos[n] = (pos < CAP) ? pos : -1;
      if (pos < CAP) elist[e * CAP + pos] = n >> 1;
    }
  }
  if (tid == 255) {
    int tot = wbase + incl;
    counts[e] = (tot < CAP) ? tot : CAP;
  }
}

// ---------------- 3. Transpose + fp32->bf16 convert (weights) ----------------
__global__ __launch_bounds__(256)
void transpose_bf16(const float* __restrict__ in, unsigned short* __restrict__ out,
                    int R, int C)
{
  __shared__ unsigned short tile[64][65];
  const int e = blockIdx.z;
  in  += (size_t)e * R * C;
  out += (size_t)e * C * R;
  const int c0 = blockIdx.x * 64;
  const int r0 = blockIdx.y * 64;
  const int tid = threadIdx.x;
#pragma unroll
  for (int i = 0; i < 16; ++i) {
    const int L = tid + i * 256;
    const int r = L >> 6, c = L & 63;
    tile[r][c] = f2bf(in[(size_t)(r0 + r) * C + c0 + c]);
  }
  __syncthreads();
#pragma unroll
  for (int i = 0; i < 16; ++i) {
    const int L = tid + i * 256;
    const int rr = L & 63, cc = L >> 6;
    out[(size_t)(c0 + cc) * R + r0 + rr] = tile[rr][cc];
  }
}

// ---------------- 4. Gather tokens per expert into contiguous bf16 rows ----------------
__global__ __launch_bounds__(64)
void moe_gather(const float* __restrict__ x, const int* __restrict__ elist,
                const int* __restrict__ counts, unsigned short* __restrict__ Xg)
{
  const int p = blockIdx.x, e = blockIdx.y;
  const int lane = threadIdx.x;
  unsigned short* dst = Xg + ((size_t)e * CAP + p) * DMODEL;
  if (p >= counts[e]) {
    ushort4 z; z.x = z.y = z.z = z.w = 0;
#pragma unroll
    for (int j = 0; j < 3; ++j) ((ushort4*)dst)[j * 64 + lane] = z;
    return;
  }
  const int tok = elist[e * CAP + p];
  const float4* src = (const float4*)(x + (size_t)tok * DMODEL);
#pragma unroll
  for (int j = 0; j < 3; ++j) {
    float4 v = src[j * 64 + lane];
    ushort4 o;
    o.x = f2bf(v.x); o.y = f2bf(v.y); o.z = f2bf(v.z); o.w = f2bf(v.w);
    ((ushort4*)dst)[j * 64 + lane] = o;
  }
}

// ---------------- 5. Grouped GEMM, 8-phase 256xBN template ----------------
// C[m,n] = A[m,:] . B[n,:] (both k-major). 512 threads = 8 waves (2 M x 4 N).
// BK=64 split into two k-halves. Half-stream order per K-tile:
//   i0 = B-kk0, i1 = A-kk0, i2 = B-kk1, i3 = A-kk1
// One half staged per phase (global_load_lds, linear dest, inverse-swizzled
// global source); ds_reads of half h in phase h+1; 16 (or 8) MFMA per phase
// lag reads by one phase; vmcnt(VMB) only at tile boundaries, before barrier.
// EPI=0: C=bf16(gelu(acc+bias)), EPI=1: C=f32(acc) (bias applied in combine).
template <int BN, int EPI, int VMB>
__global__ __launch_bounds__(512)
void moe_gemm8(const unsigned short* __restrict__ Ag, int lda,
               const unsigned short* __restrict__ Bg, int ldb,
               void* __restrict__ Cout0, void* __restrict__ Cout1, int ldc,
               const float* __restrict__ bias,
               int Nsize, int NT, int MT, int NTN, int nslice)
{
  constexpr int NR  = BN / 64;    // n-reps per wave
  constexpr int NB  = BN / 128;   // gld issues per B half
  constexpr int BNW = BN / 4;     // cols per wave
  __shared__ __align__(16) unsigned short lds[4 * 8192 + 4 * BN * 32];

  // block decode with XCD-bijective swizzle (gridDim.x % 8 == 0)
  const int nwg = gridDim.x;
  const int cpx = nwg >> 3;
  const int swz = (blockIdx.x & 7) * cpx + (blockIdx.x >> 3);
  const int per_e = nslice * MT * NTN;
  const int e = swz / per_e;
  int rdec = swz - e * per_e;
  const int ks = rdec / (MT * NTN);
  rdec -= ks * MT * NTN;
  const int mt = rdec % MT;
  const int nt = rdec / MT;
  const int m0 = mt * 256, n0 = nt * BN;
  const int kb = ks * NT * 64;

  const unsigned short* Ae = Ag + (size_t)e * CAP * lda;
  const unsigned short* Be = Bg + (size_t)e * Nsize * ldb;

  const int tid  = threadIdx.x;
  const int lane = tid & 63, wid = tid >> 6;
  const int wr = wid >> 2, wc = wid & 3;
  const int r16 = lane & 15, g4 = lane >> 4;
  const int kch8 = (g4 ^ ((lane >> 2) & 3)) * 8;   // swizzled read chunk (ushorts)

  // staging per-thread constants (dest linear, source chunk-XOR swizzled)
  const int srow  = tid >> 2;
  const int csrc8 = ((tid & 3) ^ ((tid >> 4) & 3)) * 8;
  const unsigned short* arow = Ae + (size_t)(m0 + srow) * lda + kb + csrc8;
  const unsigned short* brow = Be + (size_t)(n0 + srow) * ldb + kb + csrc8;
  const int ldst = wid * 64 * 8;                    // wave-uniform LDS base (ushorts)

  auto stageA = [&](int tt, int kh) {
    unsigned short* s = &lds[((tt & 1) * 2 + kh) * 8192];
    const unsigned short* gp = arow + tt * 64 + kh * 32;
    gld_lds16(gp,             s + ldst);
    gld_lds16(gp + 128 * lda, s + 512 * 8 + ldst);
  };
  auto stageB = [&](int tt, int kh) {
    unsigned short* s = &lds[32768 + ((tt & 1) * 2 + kh) * (BN * 32)];
    const unsigned short* gp = brow + tt * 64 + kh * 32;
    gld_lds16(gp, s + ldst);
    if constexpr (NB == 2) gld_lds16(gp + 128 * ldb, s + 512 * 8 + ldst);
  };
  auto loadA = [&](int b, int kh, int mi) -> bf16x8 {
    return *(const bf16x8*)&lds[(b * 2 + kh) * 8192 +
                                (wr * 128 + mi * 16 + r16) * 32 + kch8];
  };
  auto loadB = [&](int b, int kh, int ni) -> bf16x8 {
    return *(const bf16x8*)&lds[32768 + (b * 2 + kh) * (BN * 32) +
                                (wc * BNW + ni * 16 + r16) * 32 + kch8];
  };

  f32x4 acc[8][NR];
#pragma unroll
  for (int i = 0; i < 8; ++i)
#pragma unroll
    for (int j = 0; j < NR; ++j) acc[i][j] = (f32x4){0.f, 0.f, 0.f, 0.f};

  bf16x8 aA0[8], aA1[8], bB0[NR], bB1[NR];

  // prologue: tile0 halves i0..i3, tile1 halves i0..i2 (3 halves in flight)
  stageB(0, 0); stageA(0, 0); stageB(0, 1); stageA(0, 1);
  stageB(1, 0); stageA(1, 0); stageB(1, 1);
  if constexpr (VMB == 6) asm volatile("s_waitcnt vmcnt(6)" ::: "memory");
  else                    asm volatile("s_waitcnt vmcnt(4)" ::: "memory");
  SBAR();

  for (int t = 0; t < NT; ++t) {
    const int b = t & 1;
    // ---- phase 1: read B-kk0(t); stage A-kk1(t+1); MFMA leftover kk1 x n-hi (t-1)
#pragma unroll
    for (int ni = 0; ni < NR; ++ni) bB0[ni] = loadB(b, 0, ni);
    if (t + 1 < NT) stageA(t + 1, 1);
    SBAR(); LGKM0();
    __builtin_amdgcn_s_setprio(1);
    if (t > 0) {
#pragma unroll
      for (int mi = 0; mi < 8; ++mi)
#pragma unroll
        for (int q = 0; q < NR / 2; ++q)
          acc[mi][NR / 2 + q] = __builtin_amdgcn_mfma_f32_16x16x32_bf16(
              aA1[mi], bB1[NR / 2 + q], acc[mi][NR / 2 + q], 0, 0, 0);
    }
    __builtin_amdgcn_s_setprio(0);
    SBAR();
    // ---- phase 2: read A-kk0(t); stage B-kk0(t+2); MFMA kk0 x n-lo
#pragma unroll
    for (int mi = 0; mi < 8; ++mi) aA0[mi] = loadA(b, 0, mi);
    if (t + 2 < NT) stageB(t + 2, 0);
    SBAR(); LGKM0();
    __builtin_amdgcn_s_setprio(1);
#pragma unroll
    for (int mi = 0; mi < 8; ++mi)
#pragma unroll
      for (int q = 0; q < NR / 2; ++q)
        acc[mi][q] = __builtin_amdgcn_mfma_f32_16x16x32_bf16(
            aA0[mi], bB0[q], acc[mi][q], 0, 0, 0);
    __builtin_amdgcn_s_setprio(0);
    SBAR();
    // ---- phase 3: read B-kk1(t); stage A-kk0(t+2); MFMA kk0 x n-hi
#pragma unroll
    for (int ni = 0; ni < NR; ++ni) bB1[ni] = loadB(b, 1, ni);
    if (t + 2 < NT) stageA(t + 2, 0);
    SBAR(); LGKM0();
    __builtin_amdgcn_s_setprio(1);
#pragma unroll
    for (int mi = 0; mi < 8; ++mi)
#pragma unroll
      for (int q = 0; q < NR / 2; ++q)
        acc[mi][NR / 2 + q] = __builtin_amdgcn_mfma_f32_16x16x32_bf16(
            aA0[mi], bB0[NR / 2 + q], acc[mi][NR / 2 + q], 0, 0, 0);
    __builtin_amdgcn_s_setprio(0);
    SBAR();
    // ---- phase 4: read A-kk1(t); stage B-kk1(t+2); MFMA kk1 x n-lo
#pragma unroll
    for (int mi = 0; mi < 8; ++mi) aA1[mi] = loadA(b, 1, mi);
    if (t + 2 < NT) stageB(t + 2, 1);
    SBAR(); LGKM0();
    __builtin_amdgcn_s_setprio(1);
#pragma unroll
    for (int mi = 0; mi < 8; ++mi)
#pragma unroll
      for (int q = 0; q < NR / 2; ++q)
        acc[mi][q] = __builtin_amdgcn_mfma_f32_16x16x32_bf16(
            aA1[mi], bB1[q], acc[mi][q], 0, 0, 0);
    __builtin_amdgcn_s_setprio(0);
    if (t < NT - 2) {
      if constexpr (VMB == 6) asm volatile("s_waitcnt vmcnt(6)" ::: "memory");
      else                    asm volatile("s_waitcnt vmcnt(4)" ::: "memory");
    } else {
      VMW0();
    }
    SBAR();
  }
  // leftover: kk1 x n-hi of the last tile (still in registers)
#pragma unroll
  for (int mi = 0; mi < 8; ++mi)
#pragma unroll
    for (int q = 0; q < NR / 2; ++q)
      acc[mi][NR / 2 + q] = __builtin_amdgcn_mfma_f32_16x16x32_bf16(
          aA1[mi], bB1[NR / 2 + q], acc[mi][NR / 2 + q], 0, 0, 0);

  // ---- epilogue. C/D layout: col = lane&15, row = 4*(lane>>4)+reg ----
  const float* bvec = bias + (size_t)e * Nsize;
  if constexpr (EPI == 0) {
    unsigned short* C = (unsigned short*)Cout0 + (size_t)e * CAP * ldc;
#pragma unroll
    for (int nr = 0; nr < NR; ++nr) {
      const int gc = n0 + wc * BNW + nr * 16 + r16;
      const float bv = bvec[gc];
#pragma unroll
      for (int mi = 0; mi < 8; ++mi) {
        const int gr0 = m0 + wr * 128 + mi * 16 + 4 * g4;
#pragma unroll
        for (int reg = 0; reg < 4; ++reg) {
          float v = acc[mi][nr][reg] + bv;
          v = 0.5f * v * (1.0f + erff(v * 0.70710678118654752f));
          C[(size_t)(gr0 + reg) * ldc + gc] = f2bf(v);
        }
      }
    }
  } else {
    float* C = (float*)(ks ? Cout1 : Cout0) + (size_t)e * CAP * ldc;
#pragma unroll
    for (int nr = 0; nr < NR; ++nr) {
      const int gc = n0 + wc * BNW + nr * 16 + r16;
#pragma unroll
      for (int mi = 0; mi < 8; ++mi) {
        const int gr0 = m0 + wr * 128 + mi * 16 + 4 * g4;
#pragma unroll
        for (int reg = 0; reg < 4; ++reg)
          C[(size_t)(gr0 + reg) * ldc + gc] = acc[mi][nr][reg];
      }
    }
  }
}

// ---------------- 6. Combine: out[t] = sum over kept slots w*(Y0+Y1+b2[e]) ----------------
__global__ __launch_bounds__(192)
void moe_combine(const float* __restrict__ Y0, const float* __restrict__ Y1,
                 const float* __restrict__ b2, const int* __restrict__ eidx,
                 const float* __restrict__ pw, const int* __restrict__ slotpos,
                 float* __restrict__ out)
{
  const int t = blockIdx.x;
  const int tid = threadIdx.x;
  float4 acc; acc.x = acc.y = acc.z = acc.w = 0.f;
#pragma unroll
  for (int s = 0; s < 2; ++s) {
    const int pos = slotpos[t * 2 + s];
    if (pos >= 0) {
      const int e = eidx[t * 2 + s];
      const float w = pw[t * 2 + s];
      const size_t ro = ((size_t)e * CAP + pos) * DMODEL;
      float4 y0 = ((const float4*)(Y0 + ro))[tid];
      float4 y1 = ((const float4*)(Y1 + ro))[tid];
      float4 bv = ((const float4*)(b2 + (size_t)e * DMODEL))[tid];
      acc.x += w * (y0.x + y1.x + bv.x);
      acc.y += w * (y0.y + y1.y + bv.y);
      acc.z += w * (y0.z + y1.z + bv.z);
      acc.w += w * (y0.w + y1.w + bv.w);
    }
  }
  ((float4*)out)[(size_t)t * (DMODEL / 4) + tid] = acc;
}

// ---------------- launch ----------------
extern "C" void kernel_launch(void* const* d_in, const int* in_sizes, int n_in,
                              void* d_out, int out_size, void* d_ws, size_t ws_size,
                              hipStream_t stream)
{
  const float* x  = (const float*)d_in[0];
  const float* Wr = (const float*)d_in[1];
  const float* w1 = (const float*)d_in[2];
  const float* b1 = (const float*)d_in[3];
  const float* w2 = (const float*)d_in[4];
  const float* b2 = (const float*)d_in[5];
  float* out = (float*)d_out;

  char* ws = (char*)d_ws;
  const size_t SZ_W1T = (size_t)NEXP * HDIM * DMODEL * 2;   // 37,748,736
  const size_t SZ_W2T = (size_t)NEXP * DMODEL * HDIM * 2;   // 37,748,736
  const size_t SZ_XG  = (size_t)NEXP * CAP * DMODEL * 2;    // 18,874,368
  const size_t SZ_H   = (size_t)NEXP * CAP * HDIM * 2;      // 75,497,472
  const size_t SZ_Y   = (size_t)NEXP * CAP * DMODEL * 4;    // 37,748,736
  unsigned short* w1t = (unsigned short*)(ws);               size_t off = SZ_W1T;
  unsigned short* w2t = (unsigned short*)(ws + off);         off += SZ_W2T;
  unsigned short* Xg  = (unsigned short*)(ws + off);         off += SZ_XG;
  unsigned short* Hb  = (unsigned short*)(ws + off);         off += SZ_H;
  float*          Y0  = (float*)(ws + off);                  off += SZ_Y;
  int*   eidx    = (int*)(ws + off);                         off += (size_t)TOK * 2 * 4;
  float* pw      = (float*)(ws + off);                       off += (size_t)TOK * 2 * 4;
  int*   slotpos = (int*)(ws + off);                         off += (size_t)NFLAT * 4;
  int*   elist   = (int*)(ws + off);                         off += (size_t)NEXP * CAP * 4;
  int*   counts  = (int*)(ws + off);
  float* Y1 = (float*)w1t;   // alias: w1t (37.75 MB) is dead after GEMM1; Y1 needs exactly that

  // 1. router (fp64 logits -> exact top-2 ordering)
  moe_router<<<TOK / 4, 256, 0, stream>>>(x, Wr, eidx, pw);
  // 2. capacity assignment
  moe_assign<<<NEXP, 256, 0, stream>>>(eidx, slotpos, elist, counts);
  // 3. weight transposes (n-major bf16)
  transpose_bf16<<<dim3(HDIM / 64, DMODEL / 64, NEXP), 256, 0, stream>>>(w1, w1t, DMODEL, HDIM);
  transpose_bf16<<<dim3(DMODEL / 64, HDIM / 64, NEXP), 256, 0, stream>>>(w2, w2t, HDIM, DMODEL);
  // 4. gather per-expert token rows (bf16), zero pad rows
  moe_gather<<<dim3(CAP, NEXP), 64, 0, stream>>>(x, elist, counts, Xg);
  // 5. grouped GEMMs (8-phase template)
  //    GEMM1: [1536x3072x768] per expert, 256x256 tile -> 8*6*12 = 576 blocks
  moe_gemm8<256, 0, 6><<<576, 512, 0, stream>>>(
      Xg, DMODEL, w1t, DMODEL, Hb, Hb, HDIM, b1, HDIM, /*NT=*/12, /*MT=*/6, /*NTN=*/12, /*nslice=*/1);
  //    GEMM2: [1536x768x3072] per expert, 256x128 tile, K-split x2 -> 8*2*6*6 = 576 blocks
  moe_gemm8<128, 1, 4><<<576, 512, 0, stream>>>(
      Hb, HDIM, w2t, HDIM, Y0, Y1, DMODEL, b2, DMODEL, /*NT=*/24, /*MT=*/6, /*NTN=*/6, /*nslice=*/2);
  // 6. weighted combine (adds K-split partials + bias; deterministic)
  moe_combine<<<TOK, 192, 0, stream>>>(Y0, Y1, b2, eidx, pw, slotpos, out);
}